// Round 2
// baseline (2473.690 us; speedup 1.0000x reference)
//
#include <hip/hip_runtime.h>
#include <hip/hip_bf16.h>

// Problem constants
// inputs [512][4][124][124], conv1 w[32][4][8][8] s4 -> [512][32][30][30]
// conv2 w[64][32][4][4] s2 -> [512][64][14][14]
// conv3 w[32][64][3][3] s1 -> [512][32][12][12] -> flat 4608
// fc [512,4608] -> xs [512][512] relu
// gi = xs @ w_ih^T + b_ih : [512][1536]
// GRU T=32, N=16, H=512 ; heads A=6
// d_out: value[512] | alp[512] | ent[512] | states_out[16*512]

// ---------------- conv1 ----------------
__global__ __launch_bounds__(256) void conv1_k(const float* __restrict__ x,
        const float* __restrict__ w, const float* __restrict__ bias,
        float* __restrict__ out) {
  __shared__ float ws1[8192];               // [32 oc][4 c][8 ky][8 kx]
  for (int i = threadIdx.x; i < 8192; i += 256) ws1[i] = w[i];
  __syncthreads();
  int pidx = blockIdx.x * 256 + threadIdx.x;   // [0, 512*450)
  int n = pidx / 450;
  int q = pidx % 450;
  int oy0 = q / 30, ox0 = q % 30;
  int q1 = q + 450;
  int oy1 = q1 / 30, ox1 = q1 % 30;
  float acc0[32], acc1[32];
  #pragma unroll
  for (int oc = 0; oc < 32; ++oc) { float bb = bias[oc] * 255.0f; acc0[oc] = bb; acc1[oc] = bb; }
  for (int c = 0; c < 4; ++c) {
    for (int ky = 0; ky < 8; ++ky) {
      const float* r0 = x + ((n*4 + c)*124 + oy0*4 + ky)*124 + ox0*4;
      const float* r1 = x + ((n*4 + c)*124 + oy1*4 + ky)*124 + ox1*4;
      float4 p0 = *(const float4*)r0, p1 = *(const float4*)(r0 + 4);
      float4 p2 = *(const float4*)r1, p3 = *(const float4*)(r1 + 4);
      float v0[8] = {p0.x,p0.y,p0.z,p0.w,p1.x,p1.y,p1.z,p1.w};
      float v1[8] = {p2.x,p2.y,p2.z,p2.w,p3.x,p3.y,p3.z,p3.w};
      const float* wb = &ws1[c*64 + ky*8];
      #pragma unroll
      for (int oc = 0; oc < 32; ++oc) {
        const float* wr = wb + oc*256;
        #pragma unroll
        for (int kx = 0; kx < 8; ++kx) { acc0[oc] += v0[kx]*wr[kx]; acc1[oc] += v1[kx]*wr[kx]; }
      }
    }
  }
  const float sc = 1.0f / 255.0f;
  #pragma unroll
  for (int oc = 0; oc < 32; ++oc) {
    out[(n*32 + oc)*900 + q]       = fmaxf(acc0[oc]*sc, 0.f);
    out[(n*32 + oc)*900 + q + 450] = fmaxf(acc1[oc]*sc, 0.f);
  }
}

// ---------------- conv2 ----------------
__global__ __launch_bounds__(256) void conv2_k(const float* __restrict__ in,
        const float* __restrict__ w, const float* __restrict__ bias,
        float* __restrict__ out) {
  __shared__ float ws2[8192];               // 16 oc * 512
  int och0 = blockIdx.y * 16;
  for (int i = threadIdx.x; i < 8192; i += 256) ws2[i] = w[och0*512 + i];
  __syncthreads();
  int pidx = blockIdx.x * 256 + threadIdx.x;   // [0, 512*98)
  int n = pidx / 98;
  int q = pidx % 98;
  int oy0 = q / 14, ox0 = q % 14;
  int q1 = q + 98;
  int oy1 = q1 / 14, ox1 = q1 % 14;
  float acc0[16], acc1[16];
  #pragma unroll
  for (int oc = 0; oc < 16; ++oc) { float bb = bias[och0 + oc]; acc0[oc] = bb; acc1[oc] = bb; }
  for (int c = 0; c < 32; ++c) {
    #pragma unroll
    for (int ky = 0; ky < 4; ++ky) {
      const float* r0 = in + ((n*32 + c)*30 + oy0*2 + ky)*30 + ox0*2;
      const float* r1 = in + ((n*32 + c)*30 + oy1*2 + ky)*30 + ox1*2;
      float v0[4] = {r0[0], r0[1], r0[2], r0[3]};
      float v1[4] = {r1[0], r1[1], r1[2], r1[3]};
      const float* wb = &ws2[c*16 + ky*4];
      #pragma unroll
      for (int oc = 0; oc < 16; ++oc) {
        const float* wr = wb + oc*512;
        #pragma unroll
        for (int kx = 0; kx < 4; ++kx) { acc0[oc] += v0[kx]*wr[kx]; acc1[oc] += v1[kx]*wr[kx]; }
      }
    }
  }
  #pragma unroll
  for (int oc = 0; oc < 16; ++oc) {
    out[(n*64 + och0 + oc)*196 + q]      = fmaxf(acc0[oc], 0.f);
    out[(n*64 + och0 + oc)*196 + q + 98] = fmaxf(acc1[oc], 0.f);
  }
}

// ---------------- conv3 ----------------
__global__ __launch_bounds__(256) void conv3_k(const float* __restrict__ in,
        const float* __restrict__ w, const float* __restrict__ bias,
        float* __restrict__ out) {
  __shared__ float ws3[9216];               // 16 oc * 576
  int och0 = blockIdx.y * 16;
  for (int i = threadIdx.x; i < 9216; i += 256) ws3[i] = w[och0*576 + i];
  __syncthreads();
  int pidx = blockIdx.x * 256 + threadIdx.x;   // [0, 512*72)
  int n = pidx / 72;
  int q = pidx % 72;
  int oy0 = q / 12, ox0 = q % 12;
  int q1 = q + 72;
  int oy1 = q1 / 12, ox1 = q1 % 12;
  float acc0[16], acc1[16];
  #pragma unroll
  for (int oc = 0; oc < 16; ++oc) { float bb = bias[och0 + oc]; acc0[oc] = bb; acc1[oc] = bb; }
  for (int c = 0; c < 64; ++c) {
    #pragma unroll
    for (int ky = 0; ky < 3; ++ky) {
      const float* r0 = in + ((n*64 + c)*14 + oy0 + ky)*14 + ox0;
      const float* r1 = in + ((n*64 + c)*14 + oy1 + ky)*14 + ox1;
      float v0[3] = {r0[0], r0[1], r0[2]};
      float v1[3] = {r1[0], r1[1], r1[2]};
      const float* wb = &ws3[c*9 + ky*3];
      #pragma unroll
      for (int oc = 0; oc < 16; ++oc) {
        const float* wr = wb + oc*576;
        #pragma unroll
        for (int kx = 0; kx < 3; ++kx) { acc0[oc] += v0[kx]*wr[kx]; acc1[oc] += v1[kx]*wr[kx]; }
      }
    }
  }
  #pragma unroll
  for (int oc = 0; oc < 16; ++oc) {
    out[(n*32 + och0 + oc)*144 + q]      = fmaxf(acc0[oc], 0.f);
    out[(n*32 + och0 + oc)*144 + q + 72] = fmaxf(acc1[oc], 0.f);
  }
}

// ---------------- GEMM: C[M][N] = A[M][K] * B[N][K]^T + bias, optional ReLU ----------------
template<bool RELU>
__global__ __launch_bounds__(256) void gemm_k(const float* __restrict__ A, const float* __restrict__ B,
                                              const float* __restrict__ bias, float* __restrict__ C,
                                              int M, int N, int K) {
  __shared__ float As[32][33];
  __shared__ float Bs[32][33];
  const int tid = threadIdx.x;
  const int tx = tid & 15, ty = tid >> 4;
  const int m0 = blockIdx.y * 32, n0 = blockIdx.x * 32;
  const int lr = tid >> 3;        // 0..31
  const int lc = (tid & 7) * 4;   // 0..28
  float acc00 = 0.f, acc01 = 0.f, acc10 = 0.f, acc11 = 0.f;
  for (int k0 = 0; k0 < K; k0 += 32) {
    float4 a4 = *(const float4*)(A + (size_t)(m0 + lr)*K + k0 + lc);
    float4 b4 = *(const float4*)(B + (size_t)(n0 + lr)*K + k0 + lc);
    __syncthreads();
    As[lc+0][lr] = a4.x; As[lc+1][lr] = a4.y; As[lc+2][lr] = a4.z; As[lc+3][lr] = a4.w;
    Bs[lc+0][lr] = b4.x; Bs[lc+1][lr] = b4.y; Bs[lc+2][lr] = b4.z; Bs[lc+3][lr] = b4.w;
    __syncthreads();
    #pragma unroll
    for (int kk = 0; kk < 32; ++kk) {
      float a0 = As[kk][ty*2], a1 = As[kk][ty*2+1];
      float b0 = Bs[kk][tx*2], b1 = Bs[kk][tx*2+1];
      acc00 += a0*b0; acc01 += a0*b1; acc10 += a1*b0; acc11 += a1*b1;
    }
  }
  int m = m0 + ty*2, n = n0 + tx*2;
  float bi0 = bias[n], bi1 = bias[n+1];
  float c00 = acc00 + bi0, c01 = acc01 + bi1, c10 = acc10 + bi0, c11 = acc11 + bi1;
  if (RELU) {
    c00 = fmaxf(c00, 0.f); c01 = fmaxf(c01, 0.f);
    c10 = fmaxf(c10, 0.f); c11 = fmaxf(c11, 0.f);
  }
  C[(size_t)m*N + n] = c00;       C[(size_t)m*N + n + 1] = c01;
  C[(size_t)(m+1)*N + n] = c10;   C[(size_t)(m+1)*N + n + 1] = c11;
}

// ---------------- GRU persistent kernel (v2) ----------------
// 256 blocks x 96 threads. Block b owns j-slice {2b, 2b+1} -> 6 rows of w_hh
// (3 gates x 2 j). One flag-per-block barrier per step: block stores its own
// padded flag (release), wave 0 polls all 256 flags (acquire, 4/lane) with
// s_sleep backoff. h exchanged via agent-scope relaxed atomics (proven r1).
#define GRU_NB 256
#define FLAG_PAD 16   // 16 ints = 64 B per flag slot
__global__ __launch_bounds__(96) void gru_k(const float* __restrict__ gi, const float* __restrict__ states,
    const float* __restrict__ masks, const float* __restrict__ w_hh, const float* __restrict__ b_hh,
    float* __restrict__ outs, float* __restrict__ hbuf, int* __restrict__ flags,
    float* __restrict__ states_out) {
  __shared__ float wsm[6*516];    // pad 516: r-groups hit distinct bank quads
  __shared__ float hs[16*516];    // pad 516: n / n+8 2-way alias only (free)
  __shared__ float gh_s[6*16];
  const int b   = blockIdx.x;
  const int tid = threadIdx.x;
  const int jbase = b * 2;
  // stage this block's 6 w_hh rows (row rr = g*2 + jj)
  for (int i = tid; i < 6*512; i += 96) {
    int rr = i >> 9, k = i & 511;
    int g = rr >> 1, jj = rr & 1;
    wsm[rr*516 + k] = w_hh[(size_t)(g*512 + jbase + jj)*512 + k];
  }
  const int n = tid & 15;
  const int r = tid >> 4;          // 0..5
  const float bh = b_hh[(r >> 1)*512 + jbase + (r & 1)];
  __syncthreads();
  for (int t = 0; t < 32; ++t) {
    // stage masked h into LDS
    if (t == 0) {
      for (int i = tid; i < 8192; i += 96) {
        int nn = i >> 9, k = i & 511;
        hs[nn*516 + k] = states[i] * masks[nn];
      }
    } else {
      const float* hsrc = hbuf + (t & 1)*8192;
      for (int i = tid; i < 8192; i += 96) {
        int nn = i >> 9, k = i & 511;
        float hv = __hip_atomic_load(hsrc + i, __ATOMIC_RELAXED, __HIP_MEMORY_SCOPE_AGENT);
        hs[nn*516 + k] = hv * masks[t*16 + nn];
      }
    }
    __syncthreads();
    // gh[n][row r] = dot(h[n], w_hh_row) + b_hh
    float a0 = 0.f, a1 = 0.f, a2 = 0.f, a3 = 0.f;
    const float* wr = wsm + r*516;
    const float* hr = hs + n*516;
    #pragma unroll 8
    for (int k = 0; k < 512; k += 4) {
      float4 w4 = *(const float4*)(wr + k);
      float4 h4 = *(const float4*)(hr + k);
      a0 += w4.x*h4.x; a1 += w4.y*h4.y; a2 += w4.z*h4.z; a3 += w4.w*h4.w;
    }
    gh_s[r*16 + n] = (a0 + a1) + (a2 + a3) + bh;
    __syncthreads();
    // gate phase: 32 threads cover 16 n x 2 j
    if (tid < 32) {
      int n2 = tid & 15, j2 = tid >> 4;
      int j = jbase + j2;
      const float* gir = gi + (size_t)(t*16 + n2)*1536;
      float ghr = gh_s[(0 + j2)*16 + n2];
      float ghz = gh_s[(2 + j2)*16 + n2];
      float ghn = gh_s[(4 + j2)*16 + n2];
      float rg = 1.f / (1.f + expf(-(gir[j] + ghr)));
      float zg = 1.f / (1.f + expf(-(gir[512 + j] + ghz)));
      float ng = tanhf(gir[1024 + j] + rg*ghn);
      float hp = hs[n2*516 + j];
      float hn = (1.f - zg)*ng + zg*hp;
      outs[(size_t)(t*16 + n2)*512 + j] = hn;
      if (t < 31) {
        __hip_atomic_store(hbuf + ((t+1)&1)*8192 + n2*512 + j, hn,
                           __ATOMIC_RELAXED, __HIP_MEMORY_SCOPE_AGENT);
      } else {
        states_out[n2*512 + j] = hn;
      }
    }
    // grid barrier (skip after last step)
    if (t < 31) {
      __threadfence();
      __syncthreads();                 // drains vmem: hbuf stores done
      if (tid == 0)
        __hip_atomic_store(&flags[b*FLAG_PAD], t + 1, __ATOMIC_RELEASE, __HIP_MEMORY_SCOPE_AGENT);
      const int target = t + 1;
      if (tid < 64) {                  // wave 0 polls; wave 1 waits at barrier
        int done = 0;
        while (!done) {
          int ok = 1;
          #pragma unroll
          for (int u = 0; u < 4; ++u) {
            int v = __hip_atomic_load(&flags[(tid*4 + u)*FLAG_PAD],
                                      __ATOMIC_ACQUIRE, __HIP_MEMORY_SCOPE_AGENT);
            ok &= (v >= target);
          }
          done = __all(ok);
          if (!done) __builtin_amdgcn_s_sleep(4);
        }
      }
      __syncthreads();
    }
  }
}

// ---------------- heads ----------------
__global__ __launch_bounds__(256) void heads_k(const float* __restrict__ xs, const int* __restrict__ action,
    const float* __restrict__ aw, const float* __restrict__ ab,
    const float* __restrict__ cw, const float* __restrict__ cb, float* __restrict__ out) {
  int row  = blockIdx.x * 4 + (threadIdx.x >> 6);
  int lane = threadIdx.x & 63;
  const float* xr = xs + (size_t)row * 512;
  float acc[7];
  #pragma unroll
  for (int a = 0; a < 7; ++a) acc[a] = 0.f;
  #pragma unroll
  for (int kb = 0; kb < 8; ++kb) {
    int k = kb*64 + lane;
    float xv = xr[k];
    #pragma unroll
    for (int a = 0; a < 6; ++a) acc[a] += xv * aw[a*512 + k];
    acc[6] += xv * cw[k];
  }
  #pragma unroll
  for (int off = 32; off > 0; off >>= 1) {
    #pragma unroll
    for (int a = 0; a < 7; ++a) acc[a] += __shfl_down(acc[a], off);
  }
  if (lane == 0) {
    float lg[6];
    #pragma unroll
    for (int a = 0; a < 6; ++a) lg[a] = acc[a] + ab[a];
    float mx = lg[0];
    #pragma unroll
    for (int a = 1; a < 6; ++a) mx = fmaxf(mx, lg[a]);
    float se = 0.f;
    #pragma unroll
    for (int a = 0; a < 6; ++a) se += expf(lg[a] - mx);
    float lse = mx + logf(se);
    float ent = 0.f;
    #pragma unroll
    for (int a = 0; a < 6; ++a) { float lp = lg[a] - lse; ent -= expf(lp)*lp; }
    int ai = action[row];
    out[row]        = acc[6] + cb[0];
    out[512  + row] = lg[ai] - lse;
    out[1024 + row] = ent;
  }
}

extern "C" void kernel_launch(void* const* d_in, const int* in_sizes, int n_in,
                              void* d_out, int out_size, void* d_ws, size_t ws_size,
                              hipStream_t stream) {
  const float* x      = (const float*)d_in[0];
  const float* states = (const float*)d_in[1];
  const float* masks  = (const float*)d_in[2];
  const int*   action = (const int*)d_in[3];
  const float* c1w = (const float*)d_in[4];
  const float* c1b = (const float*)d_in[5];
  const float* c2w = (const float*)d_in[6];
  const float* c2b = (const float*)d_in[7];
  const float* c3w = (const float*)d_in[8];
  const float* c3b = (const float*)d_in[9];
  const float* fcw = (const float*)d_in[10];
  const float* fcb = (const float*)d_in[11];
  const float* wih = (const float*)d_in[12];
  const float* whh = (const float*)d_in[13];
  const float* bih = (const float*)d_in[14];
  const float* bhh = (const float*)d_in[15];
  const float* aw  = (const float*)d_in[16];
  const float* ab  = (const float*)d_in[17];
  const float* cw  = (const float*)d_in[18];
  const float* cb  = (const float*)d_in[19];
  (void)in_sizes; (void)n_in; (void)out_size; (void)ws_size;

  float* ws = (float*)d_ws;
  // layout (floats): o1[0 .. 14745600) | o2[14745600 .. 21168128)
  // after conv2, o1 region reused: o3[0..2359296) xs[2359296..2621440)
  // gi[2621440..3407872) outs[3407872..3670016) hbuf[3670016..3686400) flags@3686400
  float* o1    = ws;
  float* o2    = ws + 14745600;
  float* o3    = ws;
  float* xs    = ws + 2359296;
  float* gibuf = ws + 2621440;
  float* outs  = ws + 3407872;
  float* hbuf  = ws + 3670016;
  int*   flags = (int*)(ws + 3686400);
  float* out   = (float*)d_out;

  conv1_k<<<900, 256, 0, stream>>>(x, c1w, c1b, o1);
  conv2_k<<<dim3(196, 4), 256, 0, stream>>>(o1, c2w, c2b, o2);
  conv3_k<<<dim3(144, 2), 256, 0, stream>>>(o2, c3w, c3b, o3);
  gemm_k<true ><<<dim3(16, 16), 256, 0, stream>>>(o3, fcw, fcb, xs, 512, 512, 4608);
  gemm_k<false><<<dim3(48, 16), 256, 0, stream>>>(xs, wih, bih, gibuf, 512, 1536, 512);
  hipMemsetAsync(flags, 0, GRU_NB * FLAG_PAD * sizeof(int), stream);
  gru_k<<<GRU_NB, 96, 0, stream>>>(gibuf, states, masks, whh, bhh, outs, hbuf, flags, out + 1536);
  heads_k<<<128, 256, 0, stream>>>(outs, action, aw, ab, cw, cb, out);
}

// Round 3
// 1331.131 us; speedup vs baseline: 1.8583x; 1.8583x over previous
//
#include <hip/hip_runtime.h>
#include <hip/hip_bf16.h>

// Problem constants
// inputs [512][4][124][124], conv1 w[32][4][8][8] s4 -> [512][32][30][30]
// conv2 w[64][32][4][4] s2 -> [512][64][14][14]
// conv3 w[32][64][3][3] s1 -> [512][32][12][12] -> flat 4608
// fc [512,4608] -> xs [512][512] relu
// gi = xs @ w_ih^T + b_ih : [512][1536]
// GRU T=32, N=16, H=512 ; heads A=6
// d_out: value[512] | alp[512] | ent[512] | states_out[16*512]

// ---------------- conv1 ----------------
__global__ __launch_bounds__(256) void conv1_k(const float* __restrict__ x,
        const float* __restrict__ w, const float* __restrict__ bias,
        float* __restrict__ out) {
  __shared__ float ws1[8192];               // [32 oc][4 c][8 ky][8 kx]
  for (int i = threadIdx.x; i < 8192; i += 256) ws1[i] = w[i];
  __syncthreads();
  int pidx = blockIdx.x * 256 + threadIdx.x;   // [0, 512*450)
  int n = pidx / 450;
  int q = pidx % 450;
  int oy0 = q / 30, ox0 = q % 30;
  int q1 = q + 450;
  int oy1 = q1 / 30, ox1 = q1 % 30;
  float acc0[32], acc1[32];
  #pragma unroll
  for (int oc = 0; oc < 32; ++oc) { float bb = bias[oc] * 255.0f; acc0[oc] = bb; acc1[oc] = bb; }
  for (int c = 0; c < 4; ++c) {
    for (int ky = 0; ky < 8; ++ky) {
      const float* r0 = x + ((n*4 + c)*124 + oy0*4 + ky)*124 + ox0*4;
      const float* r1 = x + ((n*4 + c)*124 + oy1*4 + ky)*124 + ox1*4;
      float4 p0 = *(const float4*)r0, p1 = *(const float4*)(r0 + 4);
      float4 p2 = *(const float4*)r1, p3 = *(const float4*)(r1 + 4);
      float v0[8] = {p0.x,p0.y,p0.z,p0.w,p1.x,p1.y,p1.z,p1.w};
      float v1[8] = {p2.x,p2.y,p2.z,p2.w,p3.x,p3.y,p3.z,p3.w};
      const float* wb = &ws1[c*64 + ky*8];
      #pragma unroll
      for (int oc = 0; oc < 32; ++oc) {
        const float* wr = wb + oc*256;
        #pragma unroll
        for (int kx = 0; kx < 8; ++kx) { acc0[oc] += v0[kx]*wr[kx]; acc1[oc] += v1[kx]*wr[kx]; }
      }
    }
  }
  const float sc = 1.0f / 255.0f;
  #pragma unroll
  for (int oc = 0; oc < 32; ++oc) {
    out[(n*32 + oc)*900 + q]       = fmaxf(acc0[oc]*sc, 0.f);
    out[(n*32 + oc)*900 + q + 450] = fmaxf(acc1[oc]*sc, 0.f);
  }
}

// ---------------- conv2 ----------------
__global__ __launch_bounds__(256) void conv2_k(const float* __restrict__ in,
        const float* __restrict__ w, const float* __restrict__ bias,
        float* __restrict__ out) {
  __shared__ float ws2[8192];               // 16 oc * 512
  int och0 = blockIdx.y * 16;
  for (int i = threadIdx.x; i < 8192; i += 256) ws2[i] = w[och0*512 + i];
  __syncthreads();
  int pidx = blockIdx.x * 256 + threadIdx.x;   // [0, 512*98)
  int n = pidx / 98;
  int q = pidx % 98;
  int oy0 = q / 14, ox0 = q % 14;
  int q1 = q + 98;
  int oy1 = q1 / 14, ox1 = q1 % 14;
  float acc0[16], acc1[16];
  #pragma unroll
  for (int oc = 0; oc < 16; ++oc) { float bb = bias[och0 + oc]; acc0[oc] = bb; acc1[oc] = bb; }
  for (int c = 0; c < 32; ++c) {
    #pragma unroll
    for (int ky = 0; ky < 4; ++ky) {
      const float* r0 = in + ((n*32 + c)*30 + oy0*2 + ky)*30 + ox0*2;
      const float* r1 = in + ((n*32 + c)*30 + oy1*2 + ky)*30 + ox1*2;
      float v0[4] = {r0[0], r0[1], r0[2], r0[3]};
      float v1[4] = {r1[0], r1[1], r1[2], r1[3]};
      const float* wb = &ws2[c*16 + ky*4];
      #pragma unroll
      for (int oc = 0; oc < 16; ++oc) {
        const float* wr = wb + oc*512;
        #pragma unroll
        for (int kx = 0; kx < 4; ++kx) { acc0[oc] += v0[kx]*wr[kx]; acc1[oc] += v1[kx]*wr[kx]; }
      }
    }
  }
  #pragma unroll
  for (int oc = 0; oc < 16; ++oc) {
    out[(n*64 + och0 + oc)*196 + q]      = fmaxf(acc0[oc], 0.f);
    out[(n*64 + och0 + oc)*196 + q + 98] = fmaxf(acc1[oc], 0.f);
  }
}

// ---------------- conv3 ----------------
__global__ __launch_bounds__(256) void conv3_k(const float* __restrict__ in,
        const float* __restrict__ w, const float* __restrict__ bias,
        float* __restrict__ out) {
  __shared__ float ws3[9216];               // 16 oc * 576
  int och0 = blockIdx.y * 16;
  for (int i = threadIdx.x; i < 9216; i += 256) ws3[i] = w[och0*576 + i];
  __syncthreads();
  int pidx = blockIdx.x * 256 + threadIdx.x;   // [0, 512*72)
  int n = pidx / 72;
  int q = pidx % 72;
  int oy0 = q / 12, ox0 = q % 12;
  int q1 = q + 72;
  int oy1 = q1 / 12, ox1 = q1 % 12;
  float acc0[16], acc1[16];
  #pragma unroll
  for (int oc = 0; oc < 16; ++oc) { float bb = bias[och0 + oc]; acc0[oc] = bb; acc1[oc] = bb; }
  for (int c = 0; c < 64; ++c) {
    #pragma unroll
    for (int ky = 0; ky < 3; ++ky) {
      const float* r0 = in + ((n*64 + c)*14 + oy0 + ky)*14 + ox0;
      const float* r1 = in + ((n*64 + c)*14 + oy1 + ky)*14 + ox1;
      float v0[3] = {r0[0], r0[1], r0[2]};
      float v1[3] = {r1[0], r1[1], r1[2]};
      const float* wb = &ws3[c*9 + ky*3];
      #pragma unroll
      for (int oc = 0; oc < 16; ++oc) {
        const float* wr = wb + oc*576;
        #pragma unroll
        for (int kx = 0; kx < 3; ++kx) { acc0[oc] += v0[kx]*wr[kx]; acc1[oc] += v1[kx]*wr[kx]; }
      }
    }
  }
  #pragma unroll
  for (int oc = 0; oc < 16; ++oc) {
    out[(n*32 + och0 + oc)*144 + q]      = fmaxf(acc0[oc], 0.f);
    out[(n*32 + och0 + oc)*144 + q + 72] = fmaxf(acc1[oc], 0.f);
  }
}

// ---------------- GEMM: C[M][N] = A[M][K] * B[N][K]^T + bias, optional ReLU ----------------
template<bool RELU>
__global__ __launch_bounds__(256) void gemm_k(const float* __restrict__ A, const float* __restrict__ B,
                                              const float* __restrict__ bias, float* __restrict__ C,
                                              int M, int N, int K) {
  __shared__ float As[32][33];
  __shared__ float Bs[32][33];
  const int tid = threadIdx.x;
  const int tx = tid & 15, ty = tid >> 4;
  const int m0 = blockIdx.y * 32, n0 = blockIdx.x * 32;
  const int lr = tid >> 3;        // 0..31
  const int lc = (tid & 7) * 4;   // 0..28
  float acc00 = 0.f, acc01 = 0.f, acc10 = 0.f, acc11 = 0.f;
  for (int k0 = 0; k0 < K; k0 += 32) {
    float4 a4 = *(const float4*)(A + (size_t)(m0 + lr)*K + k0 + lc);
    float4 b4 = *(const float4*)(B + (size_t)(n0 + lr)*K + k0 + lc);
    __syncthreads();
    As[lc+0][lr] = a4.x; As[lc+1][lr] = a4.y; As[lc+2][lr] = a4.z; As[lc+3][lr] = a4.w;
    Bs[lc+0][lr] = b4.x; Bs[lc+1][lr] = b4.y; Bs[lc+2][lr] = b4.z; Bs[lc+3][lr] = b4.w;
    __syncthreads();
    #pragma unroll
    for (int kk = 0; kk < 32; ++kk) {
      float a0 = As[kk][ty*2], a1 = As[kk][ty*2+1];
      float b0 = Bs[kk][tx*2], b1 = Bs[kk][tx*2+1];
      acc00 += a0*b0; acc01 += a0*b1; acc10 += a1*b0; acc11 += a1*b1;
    }
  }
  int m = m0 + ty*2, n = n0 + tx*2;
  float bi0 = bias[n], bi1 = bias[n+1];
  float c00 = acc00 + bi0, c01 = acc01 + bi1, c10 = acc10 + bi0, c11 = acc11 + bi1;
  if (RELU) {
    c00 = fmaxf(c00, 0.f); c01 = fmaxf(c01, 0.f);
    c10 = fmaxf(c10, 0.f); c11 = fmaxf(c11, 0.f);
  }
  C[(size_t)m*N + n] = c00;       C[(size_t)m*N + n + 1] = c01;
  C[(size_t)(m+1)*N + n] = c10;   C[(size_t)(m+1)*N + n + 1] = c11;
}

// ---------------- GRU persistent kernel (v3) ----------------
// 256 blocks x 128 threads. Block b owns j-slice {2b, 2b+1} -> 6 rows of w_hh.
// NO cache-maintenance ops anywhere: all cross-block traffic uses RELAXED
// agent-scope atomics (sc0/sc1 bypass -> coherence point). Ordering of
// h-stores before flag-store: both issued by wave 0; explicit s_waitcnt(0)
// drains the h stores before the flag store. Poll = relaxed coalesced u64
// loads of the packed flag array by wave 0, __all-reduced, s_sleep backoff.
#define GRU_NB 256
__global__ __launch_bounds__(128) void gru_k(const float* __restrict__ gi, const float* __restrict__ states,
    const float* __restrict__ masks, const float* __restrict__ w_hh, const float* __restrict__ b_hh,
    float* __restrict__ outs, float* __restrict__ hbuf, int* __restrict__ flags,
    float* __restrict__ states_out) {
  __shared__ float wsm[6*516];    // pad 516: conflict-free (verified r2)
  __shared__ float hs[16*516];
  __shared__ float gh_s[6*16];
  const int b   = blockIdx.x;
  const int tid = threadIdx.x;
  const int jbase = b * 2;
  // stage this block's 6 w_hh rows (row rr = g*2 + jj)
  for (int i = tid; i < 6*512; i += 128) {
    int rr = i >> 9, k = i & 511;
    int g = rr >> 1, jj = rr & 1;
    wsm[rr*516 + k] = w_hh[(size_t)(g*512 + jbase + jj)*512 + k];
  }
  const int n = tid & 15;
  const int r = (tid < 96) ? (tid >> 4) : 0;   // 0..5
  const float bh = b_hh[(r >> 1)*512 + jbase + (r & 1)];
  __syncthreads();
  for (int t = 0; t < 32; ++t) {
    // ---- stage masked h into LDS ----
    if (t == 0) {
      for (int i = tid; i < 2048; i += 128) {       // float4 loads of states
        int nn = i >> 7, k = (i & 127) << 2;
        float4 h4 = *(const float4*)(states + nn*512 + k);
        float m = masks[nn];
        float* d = &hs[nn*516 + k];
        d[0] = h4.x*m; d[1] = h4.y*m; d[2] = h4.z*m; d[3] = h4.w*m;
      }
    } else {
      const unsigned long long* hsrc =
          (const unsigned long long*)(hbuf + (t & 1)*8192);
      for (int i = tid; i < 4096; i += 128) {       // u64 bypass loads
        int nn = i >> 8, k = (i & 255) << 1;
        unsigned long long u = __hip_atomic_load(hsrc + i, __ATOMIC_RELAXED,
                                                 __HIP_MEMORY_SCOPE_AGENT);
        union { unsigned long long u; float f[2]; } cv; cv.u = u;
        float m = masks[t*16 + nn];
        hs[nn*516 + k]     = cv.f[0]*m;
        hs[nn*516 + k + 1] = cv.f[1]*m;
      }
    }
    __syncthreads();
    // ---- gh[n][row r] = dot(h[n], w_hh_row) + b_hh ----
    if (tid < 96) {
      float a0 = 0.f, a1 = 0.f, a2 = 0.f, a3 = 0.f;
      const float* wr = wsm + r*516;
      const float* hr = hs + n*516;
      #pragma unroll 8
      for (int k = 0; k < 512; k += 4) {
        float4 w4 = *(const float4*)(wr + k);
        float4 h4 = *(const float4*)(hr + k);
        a0 += w4.x*h4.x; a1 += w4.y*h4.y; a2 += w4.z*h4.z; a3 += w4.w*h4.w;
      }
      gh_s[r*16 + n] = (a0 + a1) + (a2 + a3) + bh;
    }
    __syncthreads();
    // ---- gate phase: 32 threads cover 16 n x 2 j (wave 0) ----
    if (tid < 32) {
      int n2 = tid & 15, j2 = tid >> 4;
      int j = jbase + j2;
      const float* gir = gi + (size_t)(t*16 + n2)*1536;
      float ghr = gh_s[(0 + j2)*16 + n2];
      float ghz = gh_s[(2 + j2)*16 + n2];
      float ghn = gh_s[(4 + j2)*16 + n2];
      float rg = 1.f / (1.f + expf(-(gir[j] + ghr)));
      float zg = 1.f / (1.f + expf(-(gir[512 + j] + ghz)));
      float ng = tanhf(gir[1024 + j] + rg*ghn);
      float hp = hs[n2*516 + j];
      float hn = (1.f - zg)*ng + zg*hp;
      outs[(size_t)(t*16 + n2)*512 + j] = hn;
      if (t < 31) {
        __hip_atomic_store(hbuf + ((t+1)&1)*8192 + n2*512 + j, hn,
                           __ATOMIC_RELAXED, __HIP_MEMORY_SCOPE_AGENT);
      } else {
        states_out[n2*512 + j] = hn;
      }
    }
    // ---- grid barrier (skip after last step) ----
    if (t < 31) {
      const int target = t + 1;
      if (tid == 0) {
        __builtin_amdgcn_s_waitcnt(0);   // wave 0's h bypass-stores acked at coherence point
        __hip_atomic_store(&flags[b], target, __ATOMIC_RELAXED, __HIP_MEMORY_SCOPE_AGENT);
      }
      if (tid < 64) {                    // wave 0 polls all 256 packed flags
        const unsigned long long* f64 = (const unsigned long long*)flags;
        int done = 0;
        while (!done) {
          unsigned long long a = __hip_atomic_load(f64 + tid*2,     __ATOMIC_RELAXED, __HIP_MEMORY_SCOPE_AGENT);
          unsigned long long c = __hip_atomic_load(f64 + tid*2 + 1, __ATOMIC_RELAXED, __HIP_MEMORY_SCOPE_AGENT);
          int ok = ((int)(a & 0xffffffffu) >= target) &
                   ((int)(a >> 32)         >= target) &
                   ((int)(c & 0xffffffffu) >= target) &
                   ((int)(c >> 32)         >= target);
          done = __all(ok);
          if (!done) __builtin_amdgcn_s_sleep(2);
        }
      }
      __syncthreads();   // also orders this step's hs reads before next staging writes
    }
  }
}

// ---------------- heads ----------------
__global__ __launch_bounds__(256) void heads_k(const float* __restrict__ xs, const int* __restrict__ action,
    const float* __restrict__ aw, const float* __restrict__ ab,
    const float* __restrict__ cw, const float* __restrict__ cb, float* __restrict__ out) {
  int row  = blockIdx.x * 4 + (threadIdx.x >> 6);
  int lane = threadIdx.x & 63;
  const float* xr = xs + (size_t)row * 512;
  float acc[7];
  #pragma unroll
  for (int a = 0; a < 7; ++a) acc[a] = 0.f;
  #pragma unroll
  for (int kb = 0; kb < 8; ++kb) {
    int k = kb*64 + lane;
    float xv = xr[k];
    #pragma unroll
    for (int a = 0; a < 6; ++a) acc[a] += xv * aw[a*512 + k];
    acc[6] += xv * cw[k];
  }
  #pragma unroll
  for (int off = 32; off > 0; off >>= 1) {
    #pragma unroll
    for (int a = 0; a < 7; ++a) acc[a] += __shfl_down(acc[a], off);
  }
  if (lane == 0) {
    float lg[6];
    #pragma unroll
    for (int a = 0; a < 6; ++a) lg[a] = acc[a] + ab[a];
    float mx = lg[0];
    #pragma unroll
    for (int a = 1; a < 6; ++a) mx = fmaxf(mx, lg[a]);
    float se = 0.f;
    #pragma unroll
    for (int a = 0; a < 6; ++a) se += expf(lg[a] - mx);
    float lse = mx + logf(se);
    float ent = 0.f;
    #pragma unroll
    for (int a = 0; a < 6; ++a) { float lp = lg[a] - lse; ent -= expf(lp)*lp; }
    int ai = action[row];
    out[row]        = acc[6] + cb[0];
    out[512  + row] = lg[ai] - lse;
    out[1024 + row] = ent;
  }
}

extern "C" void kernel_launch(void* const* d_in, const int* in_sizes, int n_in,
                              void* d_out, int out_size, void* d_ws, size_t ws_size,
                              hipStream_t stream) {
  const float* x      = (const float*)d_in[0];
  const float* states = (const float*)d_in[1];
  const float* masks  = (const float*)d_in[2];
  const int*   action = (const int*)d_in[3];
  const float* c1w = (const float*)d_in[4];
  const float* c1b = (const float*)d_in[5];
  const float* c2w = (const float*)d_in[6];
  const float* c2b = (const float*)d_in[7];
  const float* c3w = (const float*)d_in[8];
  const float* c3b = (const float*)d_in[9];
  const float* fcw = (const float*)d_in[10];
  const float* fcb = (const float*)d_in[11];
  const float* wih = (const float*)d_in[12];
  const float* whh = (const float*)d_in[13];
  const float* bih = (const float*)d_in[14];
  const float* bhh = (const float*)d_in[15];
  const float* aw  = (const float*)d_in[16];
  const float* ab  = (const float*)d_in[17];
  const float* cw  = (const float*)d_in[18];
  const float* cb  = (const float*)d_in[19];
  (void)in_sizes; (void)n_in; (void)out_size; (void)ws_size;

  float* ws = (float*)d_ws;
  // layout (floats): o1[0 .. 14745600) | o2[14745600 .. 21168128)
  // after conv2, o1 region reused: o3[0..2359296) xs[2359296..2621440)
  // gi[2621440..3407872) outs[3407872..3670016) hbuf[3670016..3686400) flags@3686400
  float* o1    = ws;
  float* o2    = ws + 14745600;
  float* o3    = ws;
  float* xs    = ws + 2359296;
  float* gibuf = ws + 2621440;
  float* outs  = ws + 3407872;
  float* hbuf  = ws + 3670016;
  int*   flags = (int*)(ws + 3686400);
  float* out   = (float*)d_out;

  conv1_k<<<900, 256, 0, stream>>>(x, c1w, c1b, o1);
  conv2_k<<<dim3(196, 4), 256, 0, stream>>>(o1, c2w, c2b, o2);
  conv3_k<<<dim3(144, 2), 256, 0, stream>>>(o2, c3w, c3b, o3);
  gemm_k<true ><<<dim3(16, 16), 256, 0, stream>>>(o3, fcw, fcb, xs, 512, 512, 4608);
  gemm_k<false><<<dim3(48, 16), 256, 0, stream>>>(xs, wih, bih, gibuf, 512, 1536, 512);
  hipMemsetAsync(flags, 0, GRU_NB * sizeof(int), stream);
  gru_k<<<GRU_NB, 128, 0, stream>>>(gibuf, states, masks, whh, bhh, outs, hbuf, flags, out + 1536);
  heads_k<<<128, 256, 0, stream>>>(outs, action, aw, ab, cw, cb, out);
}

// Round 4
// 1319.129 us; speedup vs baseline: 1.8752x; 1.0091x over previous
//
#include <hip/hip_runtime.h>
#include <hip/hip_bf16.h>

// Problem constants
// inputs [512][4][124][124], conv1 w[32][4][8][8] s4 -> [512][32][30][30]
// conv2 w[64][32][4][4] s2 -> [512][64][14][14]
// conv3 w[32][64][3][3] s1 -> [512][32][12][12] -> flat 4608
// fc [512,4608] -> xs [512][512] relu
// gi = xs @ w_ih^T + b_ih : [512][1536]
// GRU T=32, N=16, H=512 ; heads A=6
// d_out: value[512] | alp[512] | ent[512] | states_out[16*512]

// ---------------- conv1 ----------------
__global__ __launch_bounds__(256) void conv1_k(const float* __restrict__ x,
        const float* __restrict__ w, const float* __restrict__ bias,
        float* __restrict__ out) {
  __shared__ float ws1[8192];               // [32 oc][4 c][8 ky][8 kx]
  for (int i = threadIdx.x; i < 8192; i += 256) ws1[i] = w[i];
  __syncthreads();
  int pidx = blockIdx.x * 256 + threadIdx.x;   // [0, 512*450)
  int n = pidx / 450;
  int q = pidx % 450;
  int oy0 = q / 30, ox0 = q % 30;
  int q1 = q + 450;
  int oy1 = q1 / 30, ox1 = q1 % 30;
  float acc0[32], acc1[32];
  #pragma unroll
  for (int oc = 0; oc < 32; ++oc) { float bb = bias[oc] * 255.0f; acc0[oc] = bb; acc1[oc] = bb; }
  for (int c = 0; c < 4; ++c) {
    for (int ky = 0; ky < 8; ++ky) {
      const float* r0 = x + ((n*4 + c)*124 + oy0*4 + ky)*124 + ox0*4;
      const float* r1 = x + ((n*4 + c)*124 + oy1*4 + ky)*124 + ox1*4;
      float4 p0 = *(const float4*)r0, p1 = *(const float4*)(r0 + 4);
      float4 p2 = *(const float4*)r1, p3 = *(const float4*)(r1 + 4);
      float v0[8] = {p0.x,p0.y,p0.z,p0.w,p1.x,p1.y,p1.z,p1.w};
      float v1[8] = {p2.x,p2.y,p2.z,p2.w,p3.x,p3.y,p3.z,p3.w};
      const float* wb = &ws1[c*64 + ky*8];
      #pragma unroll
      for (int oc = 0; oc < 32; ++oc) {
        const float* wr = wb + oc*256;
        #pragma unroll
        for (int kx = 0; kx < 8; ++kx) { acc0[oc] += v0[kx]*wr[kx]; acc1[oc] += v1[kx]*wr[kx]; }
      }
    }
  }
  const float sc = 1.0f / 255.0f;
  #pragma unroll
  for (int oc = 0; oc < 32; ++oc) {
    out[(n*32 + oc)*900 + q]       = fmaxf(acc0[oc]*sc, 0.f);
    out[(n*32 + oc)*900 + q + 450] = fmaxf(acc1[oc]*sc, 0.f);
  }
}

// ---------------- conv2 ----------------
__global__ __launch_bounds__(256) void conv2_k(const float* __restrict__ in,
        const float* __restrict__ w, const float* __restrict__ bias,
        float* __restrict__ out) {
  __shared__ float ws2[8192];               // 16 oc * 512
  int och0 = blockIdx.y * 16;
  for (int i = threadIdx.x; i < 8192; i += 256) ws2[i] = w[och0*512 + i];
  __syncthreads();
  int pidx = blockIdx.x * 256 + threadIdx.x;   // [0, 512*98)
  int n = pidx / 98;
  int q = pidx % 98;
  int oy0 = q / 14, ox0 = q % 14;
  int q1 = q + 98;
  int oy1 = q1 / 14, ox1 = q1 % 14;
  float acc0[16], acc1[16];
  #pragma unroll
  for (int oc = 0; oc < 16; ++oc) { float bb = bias[och0 + oc]; acc0[oc] = bb; acc1[oc] = bb; }
  for (int c = 0; c < 32; ++c) {
    #pragma unroll
    for (int ky = 0; ky < 4; ++ky) {
      const float* r0 = in + ((n*32 + c)*30 + oy0*2 + ky)*30 + ox0*2;
      const float* r1 = in + ((n*32 + c)*30 + oy1*2 + ky)*30 + ox1*2;
      float v0[4] = {r0[0], r0[1], r0[2], r0[3]};
      float v1[4] = {r1[0], r1[1], r1[2], r1[3]};
      const float* wb = &ws2[c*16 + ky*4];
      #pragma unroll
      for (int oc = 0; oc < 16; ++oc) {
        const float* wr = wb + oc*512;
        #pragma unroll
        for (int kx = 0; kx < 4; ++kx) { acc0[oc] += v0[kx]*wr[kx]; acc1[oc] += v1[kx]*wr[kx]; }
      }
    }
  }
  #pragma unroll
  for (int oc = 0; oc < 16; ++oc) {
    out[(n*64 + och0 + oc)*196 + q]      = fmaxf(acc0[oc], 0.f);
    out[(n*64 + och0 + oc)*196 + q + 98] = fmaxf(acc1[oc], 0.f);
  }
}

// ---------------- conv3 ----------------
__global__ __launch_bounds__(256) void conv3_k(const float* __restrict__ in,
        const float* __restrict__ w, const float* __restrict__ bias,
        float* __restrict__ out) {
  __shared__ float ws3[9216];               // 16 oc * 576
  int och0 = blockIdx.y * 16;
  for (int i = threadIdx.x; i < 9216; i += 256) ws3[i] = w[och0*576 + i];
  __syncthreads();
  int pidx = blockIdx.x * 256 + threadIdx.x;   // [0, 512*72)
  int n = pidx / 72;
  int q = pidx % 72;
  int oy0 = q / 12, ox0 = q % 12;
  int q1 = q + 72;
  int oy1 = q1 / 12, ox1 = q1 % 12;
  float acc0[16], acc1[16];
  #pragma unroll
  for (int oc = 0; oc < 16; ++oc) { float bb = bias[och0 + oc]; acc0[oc] = bb; acc1[oc] = bb; }
  for (int c = 0; c < 64; ++c) {
    #pragma unroll
    for (int ky = 0; ky < 3; ++ky) {
      const float* r0 = in + ((n*64 + c)*14 + oy0 + ky)*14 + ox0;
      const float* r1 = in + ((n*64 + c)*14 + oy1 + ky)*14 + ox1;
      float v0[3] = {r0[0], r0[1], r0[2]};
      float v1[3] = {r1[0], r1[1], r1[2]};
      const float* wb = &ws3[c*9 + ky*3];
      #pragma unroll
      for (int oc = 0; oc < 16; ++oc) {
        const float* wr = wb + oc*576;
        #pragma unroll
        for (int kx = 0; kx < 3; ++kx) { acc0[oc] += v0[kx]*wr[kx]; acc1[oc] += v1[kx]*wr[kx]; }
      }
    }
  }
  #pragma unroll
  for (int oc = 0; oc < 16; ++oc) {
    out[(n*32 + och0 + oc)*144 + q]      = fmaxf(acc0[oc], 0.f);
    out[(n*32 + och0 + oc)*144 + q + 72] = fmaxf(acc1[oc], 0.f);
  }
}

// ---------------- GEMM: C[M][N] = A[M][K] * B[N][K]^T + bias, optional ReLU ----------------
template<bool RELU>
__global__ __launch_bounds__(256) void gemm_k(const float* __restrict__ A, const float* __restrict__ B,
                                              const float* __restrict__ bias, float* __restrict__ C,
                                              int M, int N, int K) {
  __shared__ float As[32][33];
  __shared__ float Bs[32][33];
  const int tid = threadIdx.x;
  const int tx = tid & 15, ty = tid >> 4;
  const int m0 = blockIdx.y * 32, n0 = blockIdx.x * 32;
  const int lr = tid >> 3;        // 0..31
  const int lc = (tid & 7) * 4;   // 0..28
  float acc00 = 0.f, acc01 = 0.f, acc10 = 0.f, acc11 = 0.f;
  for (int k0 = 0; k0 < K; k0 += 32) {
    float4 a4 = *(const float4*)(A + (size_t)(m0 + lr)*K + k0 + lc);
    float4 b4 = *(const float4*)(B + (size_t)(n0 + lr)*K + k0 + lc);
    __syncthreads();
    As[lc+0][lr] = a4.x; As[lc+1][lr] = a4.y; As[lc+2][lr] = a4.z; As[lc+3][lr] = a4.w;
    Bs[lc+0][lr] = b4.x; Bs[lc+1][lr] = b4.y; Bs[lc+2][lr] = b4.z; Bs[lc+3][lr] = b4.w;
    __syncthreads();
    #pragma unroll
    for (int kk = 0; kk < 32; ++kk) {
      float a0 = As[kk][ty*2], a1 = As[kk][ty*2+1];
      float b0 = Bs[kk][tx*2], b1 = Bs[kk][tx*2+1];
      acc00 += a0*b0; acc01 += a0*b1; acc10 += a1*b0; acc11 += a1*b1;
    }
  }
  int m = m0 + ty*2, n = n0 + tx*2;
  float bi0 = bias[n], bi1 = bias[n+1];
  float c00 = acc00 + bi0, c01 = acc01 + bi1, c10 = acc10 + bi0, c11 = acc11 + bi1;
  if (RELU) {
    c00 = fmaxf(c00, 0.f); c01 = fmaxf(c01, 0.f);
    c10 = fmaxf(c10, 0.f); c11 = fmaxf(c11, 0.f);
  }
  C[(size_t)m*N + n] = c00;       C[(size_t)m*N + n + 1] = c01;
  C[(size_t)(m+1)*N + n] = c10;   C[(size_t)(m+1)*N + n + 1] = c11;
}

// ---------------- GRU persistent kernel (v4) ----------------
// 256 blocks x 128 threads. Block b owns j-slice {2b, 2b+1} -> 6 rows of w_hh.
// Centralized two-phase barrier: ONE arrive counter (atomicAdd, monotone) +
// ONE go word, both on their own cache line. Only tid 0 spins; the rest park
// at __syncthreads. All cross-block data relaxed agent-scope (bypass) atomics;
// no cache maintenance anywhere. h-stores ordered before arrive by wave-0
// s_waitcnt(0) (h producers and the arriver are the same wave).
#define GRU_NB 256
__global__ __launch_bounds__(128) void gru_k(const float* __restrict__ gi, const float* __restrict__ states,
    const float* __restrict__ masks, const float* __restrict__ w_hh, const float* __restrict__ b_hh,
    float* __restrict__ outs, float* __restrict__ hbuf, int* __restrict__ flags,
    float* __restrict__ states_out) {
  __shared__ float wsm[6*516];    // pad 516: conflict-free (verified r2)
  __shared__ float hs[16*516];
  __shared__ float gh_s[6*16];
  const int b   = blockIdx.x;
  const int tid = threadIdx.x;
  const int jbase = b * 2;
  int* cnt = flags;          // arrive counter (line 0)
  int* go  = flags + 32;     // release word (line 1, 128 B away)
  // stage this block's 6 w_hh rows (row rr = g*2 + jj)
  for (int i = tid; i < 6*512; i += 128) {
    int rr = i >> 9, k = i & 511;
    int g = rr >> 1, jj = rr & 1;
    wsm[rr*516 + k] = w_hh[(size_t)(g*512 + jbase + jj)*512 + k];
  }
  const int n = tid & 15;
  const int r = (tid < 96) ? (tid >> 4) : 0;   // 0..5
  const float bh = b_hh[(r >> 1)*512 + jbase + (r & 1)];
  __syncthreads();
  for (int t = 0; t < 32; ++t) {
    // ---- stage masked h into LDS ----
    if (t == 0) {
      for (int i = tid; i < 2048; i += 128) {       // float4 loads of states
        int nn = i >> 7, k = (i & 127) << 2;
        float4 h4 = *(const float4*)(states + nn*512 + k);
        float m = masks[nn];
        float* d = &hs[nn*516 + k];
        d[0] = h4.x*m; d[1] = h4.y*m; d[2] = h4.z*m; d[3] = h4.w*m;
      }
    } else {
      const unsigned long long* hsrc =
          (const unsigned long long*)(hbuf + (t & 1)*8192);
      for (int i = tid; i < 4096; i += 128) {       // u64 bypass loads
        int nn = i >> 8, k = (i & 255) << 1;
        unsigned long long u = __hip_atomic_load(hsrc + i, __ATOMIC_RELAXED,
                                                 __HIP_MEMORY_SCOPE_AGENT);
        union { unsigned long long u; float f[2]; } cv; cv.u = u;
        float m = masks[t*16 + nn];
        hs[nn*516 + k]     = cv.f[0]*m;
        hs[nn*516 + k + 1] = cv.f[1]*m;
      }
    }
    __syncthreads();
    // ---- gh[n][row r] = dot(h[n], w_hh_row) + b_hh ----
    if (tid < 96) {
      float a0 = 0.f, a1 = 0.f, a2 = 0.f, a3 = 0.f;
      const float* wr = wsm + r*516;
      const float* hr = hs + n*516;
      #pragma unroll 8
      for (int k = 0; k < 512; k += 4) {
        float4 w4 = *(const float4*)(wr + k);
        float4 h4 = *(const float4*)(hr + k);
        a0 += w4.x*h4.x; a1 += w4.y*h4.y; a2 += w4.z*h4.z; a3 += w4.w*h4.w;
      }
      gh_s[r*16 + n] = (a0 + a1) + (a2 + a3) + bh;
    }
    __syncthreads();
    // ---- gate phase: 32 threads cover 16 n x 2 j (wave 0) ----
    if (tid < 32) {
      int n2 = tid & 15, j2 = tid >> 4;
      int j = jbase + j2;
      const float* gir = gi + (size_t)(t*16 + n2)*1536;
      float ghr = gh_s[(0 + j2)*16 + n2];
      float ghz = gh_s[(2 + j2)*16 + n2];
      float ghn = gh_s[(4 + j2)*16 + n2];
      float rg = 1.f / (1.f + expf(-(gir[j] + ghr)));
      float zg = 1.f / (1.f + expf(-(gir[512 + j] + ghz)));
      float ng = tanhf(gir[1024 + j] + rg*ghn);
      float hp = hs[n2*516 + j];
      float hn = (1.f - zg)*ng + zg*hp;
      outs[(size_t)(t*16 + n2)*512 + j] = hn;
      if (t < 31) {
        __hip_atomic_store(hbuf + ((t+1)&1)*8192 + n2*512 + j, hn,
                           __ATOMIC_RELAXED, __HIP_MEMORY_SCOPE_AGENT);
      } else {
        states_out[n2*512 + j] = hn;
      }
    }
    // ---- centralized grid barrier (skip after last step) ----
    if (t < 31) {
      const int target = t + 1;
      if (tid == 0) {
        __builtin_amdgcn_s_waitcnt(0);   // wave 0's h bypass-stores acked at coherence point
        int old = atomicAdd(cnt, 1);     // device-scope RMW at coherence point
        if (old == GRU_NB * target - 1)
          __hip_atomic_store(go, target, __ATOMIC_RELAXED, __HIP_MEMORY_SCOPE_AGENT);
        while (__hip_atomic_load(go, __ATOMIC_RELAXED, __HIP_MEMORY_SCOPE_AGENT) < target)
          __builtin_amdgcn_s_sleep(4);
      }
      __syncthreads();   // releases the block; also orders hs reads vs next staging
    }
  }
}

// ---------------- heads ----------------
__global__ __launch_bounds__(256) void heads_k(const float* __restrict__ xs, const int* __restrict__ action,
    const float* __restrict__ aw, const float* __restrict__ ab,
    const float* __restrict__ cw, const float* __restrict__ cb, float* __restrict__ out) {
  int row  = blockIdx.x * 4 + (threadIdx.x >> 6);
  int lane = threadIdx.x & 63;
  const float* xr = xs + (size_t)row * 512;
  float acc[7];
  #pragma unroll
  for (int a = 0; a < 7; ++a) acc[a] = 0.f;
  #pragma unroll
  for (int kb = 0; kb < 8; ++kb) {
    int k = kb*64 + lane;
    float xv = xr[k];
    #pragma unroll
    for (int a = 0; a < 6; ++a) acc[a] += xv * aw[a*512 + k];
    acc[6] += xv * cw[k];
  }
  #pragma unroll
  for (int off = 32; off > 0; off >>= 1) {
    #pragma unroll
    for (int a = 0; a < 7; ++a) acc[a] += __shfl_down(acc[a], off);
  }
  if (lane == 0) {
    float lg[6];
    #pragma unroll
    for (int a = 0; a < 6; ++a) lg[a] = acc[a] + ab[a];
    float mx = lg[0];
    #pragma unroll
    for (int a = 1; a < 6; ++a) mx = fmaxf(mx, lg[a]);
    float se = 0.f;
    #pragma unroll
    for (int a = 0; a < 6; ++a) se += expf(lg[a] - mx);
    float lse = mx + logf(se);
    float ent = 0.f;
    #pragma unroll
    for (int a = 0; a < 6; ++a) { float lp = lg[a] - lse; ent -= expf(lp)*lp; }
    int ai = action[row];
    out[row]        = acc[6] + cb[0];
    out[512  + row] = lg[ai] - lse;
    out[1024 + row] = ent;
  }
}

extern "C" void kernel_launch(void* const* d_in, const int* in_sizes, int n_in,
                              void* d_out, int out_size, void* d_ws, size_t ws_size,
                              hipStream_t stream) {
  const float* x      = (const float*)d_in[0];
  const float* states = (const float*)d_in[1];
  const float* masks  = (const float*)d_in[2];
  const int*   action = (const int*)d_in[3];
  const float* c1w = (const float*)d_in[4];
  const float* c1b = (const float*)d_in[5];
  const float* c2w = (const float*)d_in[6];
  const float* c2b = (const float*)d_in[7];
  const float* c3w = (const float*)d_in[8];
  const float* c3b = (const float*)d_in[9];
  const float* fcw = (const float*)d_in[10];
  const float* fcb = (const float*)d_in[11];
  const float* wih = (const float*)d_in[12];
  const float* whh = (const float*)d_in[13];
  const float* bih = (const float*)d_in[14];
  const float* bhh = (const float*)d_in[15];
  const float* aw  = (const float*)d_in[16];
  const float* ab  = (const float*)d_in[17];
  const float* cw  = (const float*)d_in[18];
  const float* cb  = (const float*)d_in[19];
  (void)in_sizes; (void)n_in; (void)out_size; (void)ws_size;

  float* ws = (float*)d_ws;
  // layout (floats): o1[0 .. 14745600) | o2[14745600 .. 21168128)
  // after conv2, o1 region reused: o3[0..2359296) xs[2359296..2621440)
  // gi[2621440..3407872) outs[3407872..3670016) hbuf[3670016..3686400) flags@3686400
  float* o1    = ws;
  float* o2    = ws + 14745600;
  float* o3    = ws;
  float* xs    = ws + 2359296;
  float* gibuf = ws + 2621440;
  float* outs  = ws + 3407872;
  float* hbuf  = ws + 3670016;
  int*   flags = (int*)(ws + 3686400);
  float* out   = (float*)d_out;

  conv1_k<<<900, 256, 0, stream>>>(x, c1w, c1b, o1);
  conv2_k<<<dim3(196, 4), 256, 0, stream>>>(o1, c2w, c2b, o2);
  conv3_k<<<dim3(144, 2), 256, 0, stream>>>(o2, c3w, c3b, o3);
  gemm_k<true ><<<dim3(16, 16), 256, 0, stream>>>(o3, fcw, fcb, xs, 512, 512, 4608);
  gemm_k<false><<<dim3(48, 16), 256, 0, stream>>>(xs, wih, bih, gibuf, 512, 1536, 512);
  hipMemsetAsync(flags, 0, 64 * sizeof(int), stream);
  gru_k<<<GRU_NB, 128, 0, stream>>>(gibuf, states, masks, whh, bhh, outs, hbuf, flags, out + 1536);
  heads_k<<<128, 256, 0, stream>>>(outs, action, aw, ab, cw, cb, out);
}